// Round 4
// baseline (363.221 us; speedup 1.0000x reference)
//
#include <hip/hip_runtime.h>

// AssociativeScanGateLoop: h_t = f_t*h_{t-1} + i_t*v_t per (b,d) sequence.
// x: (B=4, T=8192, 3*512) fp32.  out: (4, 8192, 512) fp32.
// Three-kernel chunked scan, float4-vectorized (4 channels/thread):
//   K1 (k_partials): per-chunk affine aggregates (A, KV).
//   K1.5 (k_scan):   exclusive prefix of aggregates -> starting state per chunk.
//   K2 (k_apply):    load starting state (1 float4), recompute chunk, write out
//                    with non-temporal stores (out is never re-read; keep L3
//                    full of x cols 0/1 so K2's re-read hits L3).

#define B_    4
#define T_    8192
#define DH_   512
#define ROW4_ 384   // 1536 floats per (b,t) row = 384 float4
#define DG4_  128   // 512 floats per column = 128 float4
#define C_    512   // chunks per batch (power of two dividing T_)
#define TC_   (T_ / C_)

typedef float nat4 __attribute__((ext_vector_type(4)));  // for NT store only

__device__ __forceinline__ float sigmoid_f(float x) {
    return __fdividef(1.0f, 1.0f + __expf(-x));   // saturates gracefully
}
__device__ __forceinline__ float tanh_f(float x) {
    return 1.0f - __fdividef(2.0f, __expf(2.0f * x) + 1.0f);
}

__device__ __forceinline__ void step_agg(float xv, float gv, float& A, float& K) {
    const float s  = sigmoid_f(gv);    // input gate
    const float f  = 1.0f - s;         // forget gate
    A = f * A;
    K = f * K + tanh_f(xv) * s;
}

// K1: per-chunk aggregate (A, KV): h_out = A*h_in + KV over the chunk.
__global__ __launch_bounds__(128) void k_partials(
        const float4* __restrict__ x4,
        float4* __restrict__ aggA,
        float4* __restrict__ aggKV) {
    const int c  = blockIdx.x;
    const int b  = blockIdx.y;
    const int d4 = threadIdx.x;            // 128 threads x 4 channels
    const float4* xb = x4 + (size_t)b * T_ * ROW4_;
    const int t0 = c * TC_;

    float4 A  = make_float4(1.0f, 1.0f, 1.0f, 1.0f);
    float4 KV = make_float4(0.0f, 0.0f, 0.0f, 0.0f);
#pragma unroll 4
    for (int i = 0; i < TC_; ++i) {
        const size_t r = (size_t)(t0 + i) * ROW4_ + d4;
        const float4 xi = xb[r];
        const float4 gi = xb[r + DG4_];
        step_agg(xi.x, gi.x, A.x, KV.x);
        step_agg(xi.y, gi.y, A.y, KV.y);
        step_agg(xi.z, gi.z, A.z, KV.z);
        step_agg(xi.w, gi.w, A.w, KV.w);
    }
    const size_t idx = ((size_t)b * C_ + c) * DG4_ + d4;
    aggA[idx]  = A;
    aggKV[idx] = KV;
}

// K1.5: sequential exclusive scan over the C_ chunk aggregates per batch.
// pref[b,c] = h entering chunk c (h_init = 0). 4 blocks, 128 threads each.
__global__ __launch_bounds__(128) void k_scan(
        const float4* __restrict__ aggA,
        const float4* __restrict__ aggKV,
        float4* __restrict__ pref) {
    const int b  = blockIdx.x;
    const int d4 = threadIdx.x;

    float4 h = make_float4(0.0f, 0.0f, 0.0f, 0.0f);
    for (int c = 0; c < C_; ++c) {
        const size_t idx = ((size_t)b * C_ + c) * DG4_ + d4;
        pref[idx] = h;                      // exclusive
        const float4 a  = aggA[idx];
        const float4 kv = aggKV[idx];
        h.x = a.x * h.x + kv.x;
        h.y = a.y * h.y + kv.y;
        h.z = a.z * h.z + kv.z;
        h.w = a.w * h.w + kv.w;
    }
}

// K2: start from pref[b,c], recompute the chunk, write gated output (NT).
__global__ __launch_bounds__(128) void k_apply(
        const float4* __restrict__ x4,
        const float4* __restrict__ pref,
        float4* __restrict__ out4) {
    const int c  = blockIdx.x;
    const int b  = blockIdx.y;
    const int d4 = threadIdx.x;

    float4 h = pref[((size_t)b * C_ + c) * DG4_ + d4];

    const float4* xb = x4 + (size_t)b * T_ * ROW4_;
    float4* ob = out4 + (size_t)b * T_ * DG4_;
    const int t0 = c * TC_;

#pragma unroll 4
    for (int i = 0; i < TC_; ++i) {
        const size_t r = (size_t)(t0 + i) * ROW4_ + d4;
        const float4 xi = xb[r];
        const float4 gi = xb[r + DG4_];
        const float4 go = xb[r + 2 * DG4_];
        float4 o;
        {
            const float s = sigmoid_f(gi.x), f = 1.0f - s;
            h.x = f * h.x + tanh_f(xi.x) * s;
            o.x = tanh_f(h.x) * sigmoid_f(go.x);
        }
        {
            const float s = sigmoid_f(gi.y), f = 1.0f - s;
            h.y = f * h.y + tanh_f(xi.y) * s;
            o.y = tanh_f(h.y) * sigmoid_f(go.y);
        }
        {
            const float s = sigmoid_f(gi.z), f = 1.0f - s;
            h.z = f * h.z + tanh_f(xi.z) * s;
            o.z = tanh_f(h.z) * sigmoid_f(go.z);
        }
        {
            const float s = sigmoid_f(gi.w), f = 1.0f - s;
            h.w = f * h.w + tanh_f(xi.w) * s;
            o.w = tanh_f(h.w) * sigmoid_f(go.w);
        }
        nat4 ov = {o.x, o.y, o.z, o.w};
        __builtin_nontemporal_store(ov, (nat4*)&ob[(size_t)(t0 + i) * DG4_ + d4]);
    }
}

extern "C" void kernel_launch(void* const* d_in, const int* in_sizes, int n_in,
                              void* d_out, int out_size, void* d_ws, size_t ws_size,
                              hipStream_t stream) {
    const float4* x4 = (const float4*)d_in[0];
    float4* out4 = (float4*)d_out;

    float4* aggA  = (float4*)d_ws;                    // B_*C_*DG4_ float4 = 4 MiB
    float4* aggKV = aggA  + (size_t)B_ * C_ * DG4_;   // 4 MiB
    float4* pref  = aggKV + (size_t)B_ * C_ * DG4_;   // 4 MiB

    hipLaunchKernelGGL(k_partials, dim3(C_, B_), dim3(128), 0, stream, x4, aggA, aggKV);
    hipLaunchKernelGGL(k_scan,     dim3(B_),     dim3(128), 0, stream, aggA, aggKV, pref);
    hipLaunchKernelGGL(k_apply,    dim3(C_, B_), dim3(128), 0, stream, x4, pref, out4);
}